// Round 14
// baseline (62.547 us; speedup 1.0000x reference)
//
#include <hip/hip_runtime.h>
#include <hip/hip_bf16.h>

// NF4 double-quant dequantize + x @ W^T — "long-run streamer".
// Every global_load_lds covers 512B-contiguous global runs (2 rows x 512B per
// instr). Tri-buffered raw-packed LDS, counted vmcnt(4) across raw s_barrier
// (glls are the only VMEM outstanding at barriers; per-chunk A/scale loads
// issue BEFORE the glls so compiler waits never drain the pipeline).
// Dequant at consume (LDS->reg, r13-validated). XOR-swizzled LDS via
// pre-swizzled global source (both-sides, rule #21). x bf16 + {cs,noc}
// precomputed (r13-validated pre_kernel). KSPLIT=2 -> 2-contributor atomicAdd
// (deterministic, r8/r12-validated).

#define OUT_D 14336
#define IN_D  4096
#define B_D   32
#define KSPLIT 2
#define KRANGE (IN_D / KSPLIT)       // 2048 elems per block
#define KC 256                       // elems per chunk
#define CHUNKS (KRANGE / KC)         // 8
#define NB (OUT_D * IN_D / 64)       // 917504
#define SZ_X (B_D * IN_D)            // 131072

typedef __attribute__((ext_vector_type(4))) float f32x4;
typedef __attribute__((ext_vector_type(2))) float f32x2;
typedef __attribute__((ext_vector_type(4))) int   i32x4;
typedef __bf16 bf16x8 __attribute__((ext_vector_type(8)));
using u16 = unsigned short;

typedef const __attribute__((address_space(1))) void* gas1_t;
typedef __attribute__((address_space(3))) void* las3_t;

__device__ __forceinline__ void gll16(const void* g, void* l) {
    __builtin_amdgcn_global_load_lds((gas1_t)g, (las3_t)l, 16, 0, 0);
}

// pre: {cs,noc} for all NB blocks + x f32->bf16  (r13-validated)
__global__ __launch_bounds__(256) void pre_kernel(
    const float* __restrict__ x,
    const float* __restrict__ absmax, const float* __restrict__ code,
    const float* __restrict__ offset,
    const float* __restrict__ g_absmax, const float* __restrict__ g_code,
    u16* __restrict__ xb, f32x2* __restrict__ csn)
{
    const int i = blockIdx.x * 256 + threadIdx.x;   // < NB (grid exact)
    float am = absmax[i], cd = code[i], of = offset[i];
    float ga = g_absmax[i >> 2], gc = g_code[i >> 2];
    float cs = (am * ga) / (cd * gc);
    f32x2 v; v.x = cs; v.y = -of * cs;
    csn[i] = v;
    if (i < SZ_X) {
        __bf16 h = (__bf16)x[i];
        xb[i] = __builtin_bit_cast(u16, h);
    }
}

__global__ __launch_bounds__(256) void nf4_main(
    const u16* __restrict__ xb,       // [32][4096] bf16
    const int* __restrict__ packed,   // [N/2] raw words
    const f32x2* __restrict__ csn,    // [NB] {cs, noc}
    float* __restrict__ out)          // [32][14336] f32 (pre-zeroed)
{
    // raw packed, [32 local rows][128 words] per buffer, slot-permuted
    __shared__ int wlds[3][32 * 128];  // 48 KB -> 3 blocks/CU

    const int t      = threadIdx.x;
    const int o_base = blockIdx.x * 32;
    const int kz     = blockIdx.y;

    const int wave = t >> 6, lane = t & 63;
    const int m_base = (wave & 1) * 16, n_base = (wave >> 1) * 16;
    const int frow = lane & 15, q = lane >> 4;

    // ---- gll addressing: gll j of this wave covers local rows 2g,2g+1
    // (g = wave*4+j); lane -> row 2g+(lane>>5), slot lane&31; global source
    // unit = slot ^ (lr&7) (pre-swizzled so consume-side XOR is bank-safe).
    const int* gsrc[4];
    #pragma unroll
    for (int j = 0; j < 4; ++j) {
        int g  = wave * 4 + j;
        int lr = 2 * g + (lane >> 5);            // local row 0..31
        int su = (lane & 31) ^ (lr & 7);         // source 16B-unit 0..31
        gsrc[j] = packed + (size_t)(o_base + lr) * (IN_D / 2)
                         + kz * (KRANGE / 2) + su * 4;
    }

    // consume-side bases
    const int lrB   = n_base + frow;             // local W row for B-frag
    const int rowA  = m_base + frow;             // batch row for A-frag
    const u16*  abase = xb + rowA * IN_D + kz * KRANGE;
    const f32x2* cbase = csn + (size_t)(o_base + lrB) * 64 + kz * (KRANGE / 64);

    f32x4 acc = {0.f, 0.f, 0.f, 0.f};

    // ---- prologue: chunks 0,1 in flight (8 glls) ----
    #pragma unroll
    for (int j = 0; j < 4; ++j) gll16(gsrc[j] + 0 * 128, &wlds[0][(wave * 4 + j) * 256]);
    #pragma unroll
    for (int j = 0; j < 4; ++j) gll16(gsrc[j] + 1 * 128, &wlds[1][(wave * 4 + j) * 256]);

    #pragma unroll
    for (int C = 0; C < CHUNKS; ++C) {
        // counted wait: chunk C landed; chunk C+1 (4 glls) stays in flight
        if (C < CHUNKS - 1) asm volatile("s_waitcnt vmcnt(4)" ::: "memory");
        else                asm volatile("s_waitcnt vmcnt(0)" ::: "memory");
        __builtin_amdgcn_s_barrier();
        __builtin_amdgcn_sched_barrier(0);

        // A-frags + scales for this chunk: issued BEFORE the glls so the
        // compiler's waits for them (vmcnt(4)) never drain the gll pipeline.
        bf16x8 a[8];
        #pragma unroll
        for (int ks = 0; ks < 8; ++ks)
            a[ks] = *reinterpret_cast<const bf16x8*>(abase + C * KC + ks * 32 + q * 8);
        f32x4 sc0 = *reinterpret_cast<const f32x4*>(cbase + C * 4);      // {cs0,noc0,cs1,noc1}
        f32x4 sc1 = *reinterpret_cast<const f32x4*>(cbase + C * 4 + 2);  // {cs2,noc2,cs3,noc3}
        __builtin_amdgcn_sched_barrier(0);

        // issue chunk C+2 into buffer (C+2)%3 — last read in compute(C-1),
        // which all waves finished before this barrier: safe.
        if (C + 2 < CHUNKS) {
            #pragma unroll
            for (int j = 0; j < 4; ++j)
                gll16(gsrc[j] + (C + 2) * 128, &wlds[(C + 2) % 3][(wave * 4 + j) * 256]);
        }
        __builtin_amdgcn_sched_barrier(0);

        const int buf = C % 3;
        #pragma unroll
        for (int ks = 0; ks < 8; ++ks) {
            // B raw: 16B unit u = ks*4+q of row lrB, slot = u ^ (lrB&7)
            i32x4 braw = *reinterpret_cast<const i32x4*>(
                &wlds[buf][lrB * 128 + (((ks * 4 + q) ^ (lrB & 7)) * 4)]);
            const float cs  = (ks < 4) ? ((ks < 2) ? sc0[0] : sc0[2])
                                       : ((ks < 6) ? sc1[0] : sc1[2]);
            const float noc = (ks < 4) ? ((ks < 2) ? sc0[1] : sc0[3])
                                       : ((ks < 6) ? sc1[1] : sc1[3]);
            bf16x8 b;
            #pragma unroll
            for (int w = 0; w < 4; ++w) {
                int ww = braw[w];
                b[2 * w]     = (__bf16)fmaf((float)(ww & 15),        cs, noc);
                b[2 * w + 1] = (__bf16)fmaf((float)((ww >> 4) & 15), cs, noc);
            }
            acc = __builtin_amdgcn_mfma_f32_16x16x32_bf16(a[ks], b, acc, 0, 0, 0);
        }
    }

    // ---- epilogue: D col = lane&15 -> out col; row = q*4+i -> batch.
    // 2 contributors (kz=0,1): commutative -> deterministic.
    const int oc = o_base + n_base + frow;
    const int r0 = m_base + q * 4;
    #pragma unroll
    for (int i = 0; i < 4; ++i)
        atomicAdd(&out[(r0 + i) * OUT_D + oc], acc[i]);
}

extern "C" void kernel_launch(void* const* d_in, const int* in_sizes, int n_in,
                              void* d_out, int out_size, void* d_ws, size_t ws_size,
                              hipStream_t stream) {
    const void* px = nullptr;
    const void* ppk = nullptr;
    const void* trio[3] = {nullptr, nullptr, nullptr};
    const void* pair[2] = {nullptr, nullptr};
    int ntrio = 0, npair = 0;
    const int SZ_PK  = OUT_D * (IN_D / 2);
    const int SZ_NG  = OUT_D * (IN_D / 256);
    for (int i = 0; i < n_in; ++i) {
        int s = in_sizes[i];
        if (s == SZ_X) px = d_in[i];
        else if (s == SZ_PK) ppk = d_in[i];
        else if (s == NB) { if (ntrio < 3) trio[ntrio++] = d_in[i]; }
        else if (s == SZ_NG) { if (npair < 2) pair[npair++] = d_in[i]; }
    }
    if (!px || !ppk || ntrio != 3 || npair != 2) {
        px = d_in[0]; ppk = d_in[1];
        trio[0] = d_in[2]; trio[1] = d_in[3]; trio[2] = d_in[4];
        pair[0] = d_in[5]; pair[1] = d_in[6];
    }

    // ws layout: xb bf16 [256KB) | csn f32x2 [7.34MB)
    char* ws = (char*)d_ws;
    u16*   xb  = (u16*)ws;
    f32x2* csn = (f32x2*)(ws + 262144);

    pre_kernel<<<dim3(NB / 256), dim3(256), 0, stream>>>(
        (const float*)px,
        (const float*)trio[0], (const float*)trio[1], (const float*)trio[2],
        (const float*)pair[0], (const float*)pair[1],
        xb, csn);

    hipMemsetAsync(d_out, 0, (size_t)out_size * sizeof(float), stream);

    nf4_main<<<dim3(OUT_D / 32, KSPLIT), dim3(256), 0, stream>>>(
        xb, (const int*)ppk, csn, (float*)d_out);
}

// Round 15
// 61.633 us; speedup vs baseline: 1.0148x; 1.0148x over previous
//
#include <hip/hip_runtime.h>
#include <hip/hip_bf16.h>

// NF4 double-quant dequantize + x @ W^T — "long-run streamer".
// Every global_load_lds covers 512B-contiguous global runs (2 rows x 512B per
// instr). Tri-buffered raw-packed LDS, counted vmcnt(4) across raw s_barrier
// (glls are the only VMEM outstanding at barriers; per-chunk A/scale loads
// issue BEFORE the glls so compiler waits never drain the pipeline).
// Dequant at consume (LDS->reg, r13-validated). XOR-swizzled LDS via
// pre-swizzled global source (both-sides, rule #21). x bf16 + {cs,noc}
// precomputed (r13-validated pre_kernel). KSPLIT=2 -> 2-contributor atomicAdd
// (deterministic, r8/r12-validated).

#define OUT_D 14336
#define IN_D  4096
#define B_D   32
#define KSPLIT 2
#define KRANGE (IN_D / KSPLIT)       // 2048 elems per block
#define KC 256                       // elems per chunk
#define CHUNKS (KRANGE / KC)         // 8
#define NB (OUT_D * IN_D / 64)       // 917504
#define SZ_X (B_D * IN_D)            // 131072

typedef __attribute__((ext_vector_type(4))) float f32x4;
typedef __attribute__((ext_vector_type(2))) float f32x2;
typedef __attribute__((ext_vector_type(4))) int   i32x4;
typedef __bf16 bf16x8 __attribute__((ext_vector_type(8)));
using u16 = unsigned short;

typedef const __attribute__((address_space(1))) void* gas1_t;
typedef __attribute__((address_space(3))) void* las3_t;

__device__ __forceinline__ void gll16(const void* g, void* l) {
    __builtin_amdgcn_global_load_lds((gas1_t)g, (las3_t)l, 16, 0, 0);
}

// pre: {cs,noc} for all NB blocks + x f32->bf16  (r13-validated)
__global__ __launch_bounds__(256) void pre_kernel(
    const float* __restrict__ x,
    const float* __restrict__ absmax, const float* __restrict__ code,
    const float* __restrict__ offset,
    const float* __restrict__ g_absmax, const float* __restrict__ g_code,
    u16* __restrict__ xb, f32x2* __restrict__ csn)
{
    const int i = blockIdx.x * 256 + threadIdx.x;   // < NB (grid exact)
    float am = absmax[i], cd = code[i], of = offset[i];
    float ga = g_absmax[i >> 2], gc = g_code[i >> 2];
    float cs = (am * ga) / (cd * gc);
    f32x2 v; v.x = cs; v.y = -of * cs;
    csn[i] = v;
    if (i < SZ_X) {
        __bf16 h = (__bf16)x[i];
        xb[i] = __builtin_bit_cast(u16, h);
    }
}

__global__ __launch_bounds__(256) void nf4_main(
    const u16* __restrict__ xb,       // [32][4096] bf16
    const int* __restrict__ packed,   // [N/2] raw words
    const f32x2* __restrict__ csn,    // [NB] {cs, noc}
    float* __restrict__ out)          // [32][14336] f32 (pre-zeroed)
{
    // raw packed, [32 local rows][128 words] per buffer, slot-permuted
    __shared__ int wlds[3][32 * 128];  // 48 KB -> 3 blocks/CU

    const int t      = threadIdx.x;
    const int o_base = blockIdx.x * 32;
    const int kz     = blockIdx.y;

    const int wave = t >> 6, lane = t & 63;
    const int m_base = (wave & 1) * 16, n_base = (wave >> 1) * 16;
    const int frow = lane & 15, q = lane >> 4;

    // ---- gll addressing: gll j of this wave covers local rows 2g,2g+1
    // (g = wave*4+j); lane -> row 2g+(lane>>5), slot lane&31; global source
    // unit = slot ^ (lr&7) (pre-swizzled so consume-side XOR is bank-safe).
    const int* gsrc[4];
    #pragma unroll
    for (int j = 0; j < 4; ++j) {
        int g  = wave * 4 + j;
        int lr = 2 * g + (lane >> 5);            // local row 0..31
        int su = (lane & 31) ^ (lr & 7);         // source 16B-unit 0..31
        gsrc[j] = packed + (size_t)(o_base + lr) * (IN_D / 2)
                         + kz * (KRANGE / 2) + su * 4;
    }

    // consume-side bases
    const int lrB   = n_base + frow;             // local W row for B-frag
    const int rowA  = m_base + frow;             // batch row for A-frag
    const u16*  abase = xb + rowA * IN_D + kz * KRANGE;
    const f32x2* cbase = csn + (size_t)(o_base + lrB) * 64 + kz * (KRANGE / 64);

    f32x4 acc = {0.f, 0.f, 0.f, 0.f};

    // ---- prologue: chunks 0,1 in flight (8 glls) ----
    #pragma unroll
    for (int j = 0; j < 4; ++j) gll16(gsrc[j] + 0 * 128, &wlds[0][(wave * 4 + j) * 256]);
    #pragma unroll
    for (int j = 0; j < 4; ++j) gll16(gsrc[j] + 1 * 128, &wlds[1][(wave * 4 + j) * 256]);

    #pragma unroll
    for (int C = 0; C < CHUNKS; ++C) {
        // counted wait: chunk C landed; chunk C+1 (4 glls) stays in flight
        if (C < CHUNKS - 1) asm volatile("s_waitcnt vmcnt(4)" ::: "memory");
        else                asm volatile("s_waitcnt vmcnt(0)" ::: "memory");
        __builtin_amdgcn_s_barrier();
        __builtin_amdgcn_sched_barrier(0);

        // A-frags + scales for this chunk: issued BEFORE the glls so the
        // compiler's waits for them (vmcnt(4)) never drain the gll pipeline.
        bf16x8 a[8];
        #pragma unroll
        for (int ks = 0; ks < 8; ++ks)
            a[ks] = *reinterpret_cast<const bf16x8*>(abase + C * KC + ks * 32 + q * 8);
        f32x4 sc0 = *reinterpret_cast<const f32x4*>(cbase + C * 4);      // {cs0,noc0,cs1,noc1}
        f32x4 sc1 = *reinterpret_cast<const f32x4*>(cbase + C * 4 + 2);  // {cs2,noc2,cs3,noc3}
        __builtin_amdgcn_sched_barrier(0);

        // issue chunk C+2 into buffer (C+2)%3 — last read in compute(C-1),
        // which all waves finished before this barrier: safe.
        if (C + 2 < CHUNKS) {
            #pragma unroll
            for (int j = 0; j < 4; ++j)
                gll16(gsrc[j] + (C + 2) * 128, &wlds[(C + 2) % 3][(wave * 4 + j) * 256]);
        }
        __builtin_amdgcn_sched_barrier(0);

        const int buf = C % 3;
        #pragma unroll
        for (int ks = 0; ks < 8; ++ks) {
            // B raw: 16B unit u = ks*4+q of row lrB, slot = u ^ (lrB&7)
            i32x4 braw = *reinterpret_cast<const i32x4*>(
                &wlds[buf][lrB * 128 + (((ks * 4 + q) ^ (lrB & 7)) * 4)]);
            const float cs  = (ks < 4) ? ((ks < 2) ? sc0[0] : sc0[2])
                                       : ((ks < 6) ? sc1[0] : sc1[2]);
            const float noc = (ks < 4) ? ((ks < 2) ? sc0[1] : sc0[3])
                                       : ((ks < 6) ? sc1[1] : sc1[3]);
            bf16x8 b;
            #pragma unroll
            for (int w = 0; w < 4; ++w) {
                int ww = braw[w];
                b[2 * w]     = (__bf16)fmaf((float)(ww & 15),        cs, noc);
                b[2 * w + 1] = (__bf16)fmaf((float)((ww >> 4) & 15), cs, noc);
            }
            acc = __builtin_amdgcn_mfma_f32_16x16x32_bf16(a[ks], b, acc, 0, 0, 0);
        }
    }

    // ---- epilogue: D col = lane&15 -> out col; row = q*4+i -> batch.
    // 2 contributors (kz=0,1): commutative -> deterministic.
    const int oc = o_base + n_base + frow;
    const int r0 = m_base + q * 4;
    #pragma unroll
    for (int i = 0; i < 4; ++i)
        atomicAdd(&out[(r0 + i) * OUT_D + oc], acc[i]);
}

extern "C" void kernel_launch(void* const* d_in, const int* in_sizes, int n_in,
                              void* d_out, int out_size, void* d_ws, size_t ws_size,
                              hipStream_t stream) {
    const void* px = nullptr;
    const void* ppk = nullptr;
    const void* trio[3] = {nullptr, nullptr, nullptr};
    const void* pair[2] = {nullptr, nullptr};
    int ntrio = 0, npair = 0;
    const int SZ_PK  = OUT_D * (IN_D / 2);
    const int SZ_NG  = OUT_D * (IN_D / 256);
    for (int i = 0; i < n_in; ++i) {
        int s = in_sizes[i];
        if (s == SZ_X) px = d_in[i];
        else if (s == SZ_PK) ppk = d_in[i];
        else if (s == NB) { if (ntrio < 3) trio[ntrio++] = d_in[i]; }
        else if (s == SZ_NG) { if (npair < 2) pair[npair++] = d_in[i]; }
    }
    if (!px || !ppk || ntrio != 3 || npair != 2) {
        px = d_in[0]; ppk = d_in[1];
        trio[0] = d_in[2]; trio[1] = d_in[3]; trio[2] = d_in[4];
        pair[0] = d_in[5]; pair[1] = d_in[6];
    }

    // ws layout: xb bf16 [256KB) | csn f32x2 [7.34MB)
    char* ws = (char*)d_ws;
    u16*   xb  = (u16*)ws;
    f32x2* csn = (f32x2*)(ws + 262144);

    pre_kernel<<<dim3(NB / 256), dim3(256), 0, stream>>>(
        (const float*)px,
        (const float*)trio[0], (const float*)trio[1], (const float*)trio[2],
        (const float*)pair[0], (const float*)pair[1],
        xb, csn);

    hipMemsetAsync(d_out, 0, (size_t)out_size * sizeof(float), stream);

    nf4_main<<<dim3(OUT_D / 32, KSPLIT), dim3(256), 0, stream>>>(
        xb, (const int*)ppk, csn, (float*)d_out);
}

// Round 16
// 55.469 us; speedup vs baseline: 1.1276x; 1.1111x over previous
//
#include <hip/hip_runtime.h>
#include <hip/hip_bf16.h>

// NF4 double-quant dequantize + x @ W^T — persistent never-drain streamer.
// 512 persistent blocks x 14 tiles; gll pipeline (4 LDS buffers, lookahead 2)
// spans tile boundaries. ALL per-iter register VMEM (A-frags, scales) for
// tile i+1 issues early so compiler use-waits are vmcnt(18), never 0 (the
// r14/r15 silent drain). Manual waits = exact FIFO literals per iteration.
// x bf16 + {cs,noc} + out-zeroing in one pre-kernel. atomicAdd flush per tile.

#define OUT_D 14336
#define IN_D  4096
#define B_D   32
#define NB    (OUT_D * IN_D / 64)     // 917504
#define SZ_X  (B_D * IN_D)            // 131072
#define SZ_OUT (B_D * OUT_D)          // 458752
#define NBLK  512
#define TPB   14                      // tiles per block; 512*14 = 7168 = 448*16

typedef __attribute__((ext_vector_type(4))) float f32x4;
typedef __attribute__((ext_vector_type(2))) float f32x2;
typedef __attribute__((ext_vector_type(4))) int   i32x4;
typedef __bf16 bf16x8 __attribute__((ext_vector_type(8)));
using u16 = unsigned short;

typedef const __attribute__((address_space(1))) void* gas1_t;
typedef __attribute__((address_space(3))) void* las3_t;

__device__ __forceinline__ void gll16(const void* g, void* l) {
    __builtin_amdgcn_global_load_lds((gas1_t)g, (las3_t)l, 16, 0, 0);
}

// pre: {cs,noc} for all NB blocks, x f32->bf16, out zeroing (one dispatch)
__global__ __launch_bounds__(256) void pre_kernel(
    const float* __restrict__ x,
    const float* __restrict__ absmax, const float* __restrict__ code,
    const float* __restrict__ offset,
    const float* __restrict__ g_absmax, const float* __restrict__ g_code,
    u16* __restrict__ xb, f32x2* __restrict__ csn, float* __restrict__ out)
{
    const int i = blockIdx.x * 256 + threadIdx.x;   // < NB (grid exact)
    float am = absmax[i], cd = code[i], of = offset[i];
    float ga = g_absmax[i >> 2], gc = g_code[i >> 2];
    float cs = (am * ga) / (cd * gc);
    f32x2 v; v.x = cs; v.y = -of * cs;
    csn[i] = v;
    if (i < SZ_X) {
        __bf16 h = (__bf16)x[i];
        xb[i] = __builtin_bit_cast(u16, h);
    }
    if (i < SZ_OUT) out[i] = 0.f;
}

__global__ __launch_bounds__(256) void nf4_main(
    const u16* __restrict__ xb,       // [32][4096] bf16
    const int* __restrict__ packed,   // [N/2] raw words
    const f32x2* __restrict__ csn,    // [NB] {cs, noc}
    float* __restrict__ out)          // [32][14336] f32 (pre-zeroed)
{
    __shared__ int wlds[4][32 * 128];  // 64 KB, 4-deep

    const int t = threadIdx.x, wave = t >> 6, lane = t & 63;
    const int frow = lane & 15, q = lane >> 4, half = lane >> 5;
    const int n_base = (wave >> 1) * 16, m_base = (wave & 1) * 16;
    const int lrB  = n_base + frow;          // local W row this lane consumes
    const int bswz = lrB & 7;                // consume-side XOR
    const int tau0 = blockIdx.x * TPB;

    int rowj[4], suj[4];                     // per-gll row / swizzled src unit
    #pragma unroll
    for (int j = 0; j < 4; ++j) {
        rowj[j] = wave * 8 + 2 * j + half;
        suj[j]  = (lane & 31) ^ (rowj[j] & 7);
    }

    bf16x8 aA[8], aB[8];
    f32x4  sA0, sA1, sB0, sB1;

#define ISSUE_GLL(I) { \
    int tau = tau0 + (I); int s_ = tau >> 4, kz_ = tau & 15; \
    _Pragma("unroll") \
    for (int j = 0; j < 4; ++j) { \
        const int* src = packed + (size_t)(s_ * 32 + rowj[j]) * 2048 \
                                + kz_ * 128 + suj[j] * 4; \
        gll16(src, &wlds[(I) & 3][(wave * 8 + 2 * j) * 128]); \
    } }

#define ISSUE_A(AP, S0, S1, I) { \
    int tau = tau0 + (I); int s_ = tau >> 4, kz_ = tau & 15; \
    const u16* ab = xb + (m_base + frow) * IN_D + kz_ * 256 + q * 8; \
    _Pragma("unroll") \
    for (int ks = 0; ks < 8; ++ks) \
        AP[ks] = *reinterpret_cast<const bf16x8*>(ab + ks * 32); \
    const f32x4* cb = reinterpret_cast<const f32x4*>( \
        csn + (size_t)(s_ * 32 + lrB) * 64 + kz_ * 4); \
    S0 = cb[0]; S1 = cb[1]; }

#define COMPUTE(AP, S0, S1, I) { \
    int tau = tau0 + (I); int s_ = tau >> 4; \
    f32x4 acc = {0.f, 0.f, 0.f, 0.f}; \
    _Pragma("unroll") \
    for (int ks = 0; ks < 8; ++ks) { \
        i32x4 braw = *reinterpret_cast<const i32x4*>( \
            &wlds[(I) & 3][lrB * 128 + (((ks * 4 + q) ^ bswz) * 4)]); \
        const float cs_  = (ks < 2) ? S0[0] : (ks < 4) ? S0[2] \
                         : (ks < 6) ? S1[0] : S1[2]; \
        const float noc_ = (ks < 2) ? S0[1] : (ks < 4) ? S0[3] \
                         : (ks < 6) ? S1[1] : S1[3]; \
        bf16x8 b; \
        _Pragma("unroll") \
        for (int w = 0; w < 4; ++w) { \
            int ww = braw[w]; \
            b[2 * w]     = (__bf16)fmaf((float)(ww & 15),        cs_, noc_); \
            b[2 * w + 1] = (__bf16)fmaf((float)((ww >> 4) & 15), cs_, noc_); \
        } \
        acc = __builtin_amdgcn_mfma_f32_16x16x32_bf16(AP[ks], b, acc, 0, 0, 0); \
    } \
    const int oc = s_ * 32 + lrB; \
    const int r0 = m_base + q * 4; \
    _Pragma("unroll") \
    for (int ii = 0; ii < 4; ++ii) \
        atomicAdd(&out[(r0 + ii) * OUT_D + oc], acc[ii]); }

// BODY: wait (exact FIFO literal), barrier, issue gll(i+2), issue A(i+1),
// then compute(i). sched_barrier pins the issue section above the compute.
#define BODY(I, VM, ACUR, SC0, SC1, ANXT, SN0, SN1) { \
    asm volatile("s_waitcnt vmcnt(" #VM ")" ::: "memory"); \
    __builtin_amdgcn_s_barrier(); \
    __builtin_amdgcn_sched_barrier(0); \
    if ((I) + 2 < TPB) ISSUE_GLL((I) + 2); \
    if ((I) + 1 < TPB) ISSUE_A(ANXT, SN0, SN1, (I) + 1); \
    __builtin_amdgcn_sched_barrier(0); \
    COMPUTE(ACUR, SC0, SC1, (I)); }

    // prologue: glls for tiles 0,1 + A(0)
    ISSUE_GLL(0)
    ISSUE_GLL(1)
    ISSUE_A(aA, sA0, sA1, 0)

    // 14 explicit bodies; vmcnt literals from FIFO accounting:
    // iter0: newer-than-gll(0) = gll(1)4 + A(0)10 = 14
    // iter1: = A(0)10 + gll(2)4 + A(1)10 + atm(0)4 = 28
    // steady (2..12): = A10 + atm4 + gll4 + A10 + atm4 = 32
    // iter13 (gll(14),A(14) skipped): = A(12)10+atm(11)4+A(13)10+atm(12)4 = 28
    BODY(0,  14, aA, sA0, sA1, aB, sB0, sB1)
    BODY(1,  28, aB, sB0, sB1, aA, sA0, sA1)
    BODY(2,  32, aA, sA0, sA1, aB, sB0, sB1)
    BODY(3,  32, aB, sB0, sB1, aA, sA0, sA1)
    BODY(4,  32, aA, sA0, sA1, aB, sB0, sB1)
    BODY(5,  32, aB, sB0, sB1, aA, sA0, sA1)
    BODY(6,  32, aA, sA0, sA1, aB, sB0, sB1)
    BODY(7,  32, aB, sB0, sB1, aA, sA0, sA1)
    BODY(8,  32, aA, sA0, sA1, aB, sB0, sB1)
    BODY(9,  32, aB, sB0, sB1, aA, sA0, sA1)
    BODY(10, 32, aA, sA0, sA1, aB, sB0, sB1)
    BODY(11, 32, aB, sB0, sB1, aA, sA0, sA1)
    BODY(12, 32, aA, sA0, sA1, aB, sB0, sB1)
    BODY(13, 28, aB, sB0, sB1, aA, sA0, sA1)

#undef ISSUE_GLL
#undef ISSUE_A
#undef COMPUTE
#undef BODY
}

extern "C" void kernel_launch(void* const* d_in, const int* in_sizes, int n_in,
                              void* d_out, int out_size, void* d_ws, size_t ws_size,
                              hipStream_t stream) {
    const void* px = nullptr;
    const void* ppk = nullptr;
    const void* trio[3] = {nullptr, nullptr, nullptr};
    const void* pair[2] = {nullptr, nullptr};
    int ntrio = 0, npair = 0;
    const int SZ_PK = OUT_D * (IN_D / 2);
    const int SZ_NG = OUT_D * (IN_D / 256);
    for (int i = 0; i < n_in; ++i) {
        int s = in_sizes[i];
        if (s == SZ_X) px = d_in[i];
        else if (s == SZ_PK) ppk = d_in[i];
        else if (s == NB) { if (ntrio < 3) trio[ntrio++] = d_in[i]; }
        else if (s == SZ_NG) { if (npair < 2) pair[npair++] = d_in[i]; }
    }
    if (!px || !ppk || ntrio != 3 || npair != 2) {
        px = d_in[0]; ppk = d_in[1];
        trio[0] = d_in[2]; trio[1] = d_in[3]; trio[2] = d_in[4];
        pair[0] = d_in[5]; pair[1] = d_in[6];
    }

    // ws layout: xb bf16 [256KB) | csn f32x2 [7.34MB)
    char* ws = (char*)d_ws;
    u16*   xb  = (u16*)ws;
    f32x2* csn = (f32x2*)(ws + 262144);

    pre_kernel<<<dim3(NB / 256), dim3(256), 0, stream>>>(
        (const float*)px,
        (const float*)trio[0], (const float*)trio[1], (const float*)trio[2],
        (const float*)pair[0], (const float*)pair[1],
        xb, csn, (float*)d_out);

    nf4_main<<<dim3(NBLK), dim3(256), 0, stream>>>(
        xb, (const int*)ppk, csn, (float*)d_out);
}